// Round 8
// baseline (580.608 us; speedup 1.0000x reference)
//
#include <hip/hip_runtime.h>
#include <hip/hip_fp16.h>

// Problem constants (from reference)
#define I_CNT 100000
#define U_CNT 131072
#define E_DIM 64
#define IE (I_CNT * E_DIM)          // 6,400,000 floats
#define UE ((size_t)U_CNT * E_DIM)  // 8,388,608 floats

#define NPH 4      // dim-phases: 4 blocks of 16 dims; 3.2 MB/block < 4 MB L2/XCD
#define DEPTH 32   // fp32-fallback ring depth

// ---------------- threefry2x32 (verified vs Random123 test vector) ----------------
__device__ __forceinline__ unsigned rotl32(unsigned v, int n) {
    return (v << n) | (v >> (32 - n));
}
__device__ __forceinline__ void threefry2x32(unsigned k0, unsigned k1,
                                             unsigned x0, unsigned x1,
                                             unsigned& o0, unsigned& o1) {
    unsigned k2 = k0 ^ k1 ^ 0x1BD11BDAu;
    x0 += k0; x1 += k1;
#define RND(r) { x0 += x1; x1 = rotl32(x1, r); x1 ^= x0; }
    RND(13) RND(15) RND(26) RND(6)   x0 += k1; x1 += k2 + 1u;
    RND(17) RND(29) RND(16) RND(24)  x0 += k2; x1 += k0 + 2u;
    RND(13) RND(15) RND(26) RND(6)   x0 += k0; x1 += k1 + 3u;
    RND(17) RND(29) RND(16) RND(24)  x0 += k1; x1 += k2 + 4u;
    RND(13) RND(15) RND(26) RND(6)   x0 += k2; x1 += k0 + 5u;
#undef RND
    o0 = x0; o1 = x1;
}

// Dropout mask, MEASURED (R8 discriminator probe): ctr=(0,e), XOR fold,
// u = bitcast((bits>>9)|0x3f800000)-1; keep iff u < 0.8; rescale 1/0.8.
// Pure function of the ORIGINAL edge index e -> phase-replication safe.
__device__ __forceinline__ float dropout_mul(unsigned e) {
    unsigned o0, o1;
    threefry2x32(0u, 42u, 0u, e, o0, o1);
    const unsigned bits = o0 ^ o1;
    const float u = __uint_as_float((bits >> 9) | 0x3f800000u) - 1.0f;
    return (u < 0.8f) ? 1.25f : 0.0f;
}

// Compile-time-index lane broadcasts -> v_readlane with immediate (uniform result).
__device__ __forceinline__ int rl_i(int v, int l) {
    return __builtin_amdgcn_readlane(v, l);
}
__device__ __forceinline__ float rl_f(float v, int l) {
    return __int_as_float(__builtin_amdgcn_readlane(__float_as_int(v), l));
}

// fp16 pack/unpack (RTN via __float2half); unpack+fmaf is the v_fma_mix pattern.
__device__ __forceinline__ float2 unpack_h2(unsigned u) {
    float2 f;
    f.x = __half2float(__ushort_as_half((unsigned short)(u & 0xffffu)));
    f.y = __half2float(__ushort_as_half((unsigned short)(u >> 16)));
    return f;
}
__device__ __forceinline__ unsigned pack_h2(float a, float b) {
    const unsigned ha = __half_as_ushort(__float2half(a));
    const unsigned hb = __half_as_ushort(__float2half(b));
    return ha | (hb << 16);
}

// ---------------- row_ptr builder (rows are sorted) ----------------
__global__ void build_row_ptr(const int* __restrict__ rows,
                              int* __restrict__ row_ptr,
                              int nnz, int n_rows) {
    const int e = blockIdx.x * blockDim.x + threadIdx.x;
    if (e >= nnz) return;
    const int r  = rows[e];
    const int rp = (e == 0) ? -1 : rows[e - 1];
    for (int q = rp + 1; q <= r; ++q) row_ptr[q] = e;
    if (e == nnz - 1) {
        for (int q = r + 1; q <= n_rows; ++q) row_ptr[q] = nnz;
    }
}

// ---------------- URM value premask (tier-1): vals * dropout, once ----------------
__global__ __launch_bounds__(256) void mask_vals(const float* __restrict__ vals,
                                                 float* __restrict__ out, int nnz) {
    const int e = blockIdx.x * blockDim.x + threadIdx.x;
    if (e >= nnz) return;
    __builtin_nontemporal_store(vals[e] * dropout_mul((unsigned)e), &out[e]);
}

// ---------------- fp32 -> fp16 convert, DIM-BLOCKED layout ----------------
// out is [NPH][I_CNT][16] fp16: block b holds dims 16b..16b+15 of every row.
__global__ __launch_bounds__(256) void f32_to_f16_blk(const float4* __restrict__ in,
                                                      unsigned short* __restrict__ out,
                                                      int n4) {
    const int i = blockIdx.x * blockDim.x + threadIdx.x;
    if (i >= n4) return;
    const int r   = i >> 4;   // row
    const int ii  = i & 15;   // dim-quad 4ii..4ii+3
    const int blk = ii >> 2;  // 16-dim block
    const int mm  = ii & 3;
    const float4 f = in[i];
    const unsigned long long lo = pack_h2(f.x, f.y);
    const unsigned long long hi = pack_h2(f.z, f.w);
    unsigned short* dst = out + ((size_t)blk * I_CNT + r) * 16 + (mm << 2);
    __builtin_nontemporal_store(lo | (hi << 32), (unsigned long long*)dst);
}

// ---------------- phased dim-blocked fp16 CSR SpMM ----------------
// Gather source xh is [NPH][I_CNT][16] fp16; phase p (from blockIdx) gathers
// ONLY block p (3.2 MB -> L2-resident per XCD). 16 edge-groups x 4 lanes x
// dwordx2 (4 dims/lane) -> ONE instruction gathers SIXTEEN x-rows. Slot
// preload (clamped padding, original-edge-index dropout), cold overflow,
// straight-line issue-all-then-consume pipeline preserved from the verified
// round-6 kernel. Flush: 4-level xor butterfly over the 16 groups; lanes 0-3
// store float4 fp32 (standard layout, dim offset 16*phase) and/or packed
// fp16 (blocked layout, for the next hop). No memsets, no atomics.
// REQUIRES SLOTS % 16 == 0 (flush aligns with load boundaries).
template <bool DROPOUT, int NROWS, int SLOTS, bool OUT32, bool OUT16>
__global__ __launch_bounds__(256) void spmm_ph(const float* __restrict__ vals,
                                               const int* __restrict__ row_ptr,
                                               const int* __restrict__ cols,
                                               const unsigned short* __restrict__ xh,
                                               float* __restrict__ y32,
                                               unsigned short* __restrict__ y16,
                                               int n_rows, int nnz, int bpp) {
    constexpr int T   = NROWS * SLOTS;  // edge slots per wave (<= 64)
    constexpr int LDN = T / 16;         // gather instructions per wave
    constexpr int LPR = SLOTS / 16;     // loads per row (flush cadence)
    static_assert(T <= 64 && (SLOTS % 16) == 0, "slots must 16-align");

    const int lane  = threadIdx.x & 63;
    const int phase = blockIdx.x / bpp;            // wave-uniform
    const int lblk  = blockIdx.x - phase * bpp;
    const int wave  = lblk * (blockDim.x >> 6) + (threadIdx.x >> 6);
    const int r0    = wave * NROWS;
    if (r0 >= n_rows) return;

    // --- preload: lane j owns slot j (verified slot mapping) ---
    const int q  = min(lane / SLOTS, NROWS - 1);
    const int j  = lane - q * SLOTS;
    const int rq = r0 + q;

    const int s   = row_ptr[rq];
    const int e   = row_ptr[rq + 1];
    const int len = e - s;

    int ce = s + min(j, max(len - 1, 0));
    ce = min(ce, nnz - 1);
    const int idx = __builtin_nontemporal_load(&cols[ce]);
    float v;
    {
        const int ve = min(s + j, nnz - 1);
        float vv = __builtin_nontemporal_load(&vals[ve]);
        if (DROPOUT) vv *= dropout_mul((unsigned)ve);
        v = (j < len) ? vv : 0.0f;
    }
    const int coff = idx << 5;  // byte offset of the 32-B block-row

    // --- consumer mapping: group g = edge 16k+g; lane holds dims 4m..4m+3 ---
    const int g = lane >> 2;    // edge-group 0..15
    const int m = lane & 3;     // dim-quad within the 16-dim block
    const char* __restrict__ xb =
        (const char*)xh + (size_t)phase * ((size_t)I_CNT * 32);

    // COLD path: rows longer than SLOTS (rare). Lanes g==0 (4 lanes = 16 dims).
    float4 ovf[NROWS];
#pragma unroll
    for (int qq = 0; qq < NROWS; ++qq) ovf[qq] = make_float4(0.f, 0.f, 0.f, 0.f);
    if (__any(len > SLOTS)) {
#pragma unroll
        for (int qq = 0; qq < NROWS; ++qq) {
            const int rs = rl_i(s, qq * SLOTS);
            const int re = rl_i(e, qq * SLOTS);
            for (int t = rs + SLOTS; t < re; ++t) {
                if (g == 0) {
                    const int c = cols[t];
                    float vv = vals[t];
                    if (DROPOUT) vv *= dropout_mul((unsigned)t);
                    const uint2 u = *(const uint2*)(xb + (c << 5) + (m << 3));
                    const float2 f01 = unpack_h2(u.x);
                    const float2 f23 = unpack_h2(u.y);
                    ovf[qq].x = fmaf(vv, f01.x, ovf[qq].x);
                    ovf[qq].y = fmaf(vv, f01.y, ovf[qq].y);
                    ovf[qq].z = fmaf(vv, f23.x, ovf[qq].z);
                    ovf[qq].w = fmaf(vv, f23.y, ovf[qq].w);
                }
            }
        }
    }

    // HOT path: issue all LDN gathers (16 rows / instruction) up front.
    uint2 xq[LDN];
#pragma unroll
    for (int k = 0; k < LDN; ++k) {
        const int co = __shfl(coff, 16 * k + g);  // ds_bpermute (LDS pipe)
        xq[k] = *(const uint2*)(xb + co + (m << 3));
    }

    float4 acc = make_float4(0.f, 0.f, 0.f, 0.f);
#pragma unroll
    for (int k = 0; k < LDN; ++k) {
        const float vv = __shfl(v, 16 * k + g);   // ds_bpermute (LDS pipe)
        const float2 f01 = unpack_h2(xq[k].x);
        const float2 f23 = unpack_h2(xq[k].y);
        acc.x = fmaf(vv, f01.x, acc.x);
        acc.y = fmaf(vv, f01.y, acc.y);
        acc.z = fmaf(vv, f23.x, acc.z);
        acc.w = fmaf(vv, f23.y, acc.w);
        if ((k % LPR) == LPR - 1) {               // compile-time flush point
            const int qk = k / LPR;               // compile-time row-of-group
            float ax = acc.x + ovf[qk].x;
            float ay = acc.y + ovf[qk].y;
            float az = acc.z + ovf[qk].z;
            float aw = acc.w + ovf[qk].w;
            // reduce over the 16 edge-groups (lane bits 2..5)
            ax += __shfl_xor(ax, 4); ax += __shfl_xor(ax, 8);
            ax += __shfl_xor(ax, 16); ax += __shfl_xor(ax, 32);
            ay += __shfl_xor(ay, 4); ay += __shfl_xor(ay, 8);
            ay += __shfl_xor(ay, 16); ay += __shfl_xor(ay, 32);
            az += __shfl_xor(az, 4); az += __shfl_xor(az, 8);
            az += __shfl_xor(az, 16); az += __shfl_xor(az, 32);
            aw += __shfl_xor(aw, 4); aw += __shfl_xor(aw, 8);
            aw += __shfl_xor(aw, 16); aw += __shfl_xor(aw, 32);
            const int row = r0 + qk;
            if (lane < 4) {  // g==0, m==lane
                if constexpr (OUT32) {
                    *(float4*)(y32 + (size_t)row * E_DIM + phase * 16 + (m << 2)) =
                        make_float4(ax, ay, az, aw);
                }
                if constexpr (OUT16) {
                    const unsigned px = pack_h2(ax, ay);
                    const unsigned py = pack_h2(az, aw);
                    *(uint2*)(y16 + ((size_t)phase * n_rows + row) * 16 + (m << 2)) =
                        make_uint2(px, py);
                }
            }
            acc = make_float4(0.f, 0.f, 0.f, 0.f);
        }
    }
    (void)y32; (void)y16;
}

// ---------------- fp32 fallback (verified round-3 kernel, unchanged) ----------------
template <bool DROPOUT, int NROWS, int SLOTS>
__global__ __launch_bounds__(256) void spmm_slots(const float* __restrict__ vals,
                                                  const int* __restrict__ row_ptr,
                                                  const int* __restrict__ cols,
                                                  const float* __restrict__ x,
                                                  float* __restrict__ y,
                                                  int n_rows, int nnz) {
    constexpr int T = NROWS * SLOTS;
    static_assert(T <= 64, "slots must fit one wave");
    constexpr int RING = (DEPTH < T) ? DEPTH : T;

    const int lane = threadIdx.x & 63;
    const int wave = blockIdx.x * (blockDim.x >> 6) + (threadIdx.x >> 6);
    const int r0   = wave * NROWS;
    if (r0 >= n_rows) return;

    const int q  = min(lane / SLOTS, NROWS - 1);
    const int j  = lane - q * SLOTS;
    const int rq = r0 + q;

    const int s   = row_ptr[rq];
    const int e   = row_ptr[rq + 1];
    const int len = e - s;

    int ce = s + min(j, max(len - 1, 0));
    ce = min(ce, nnz - 1);
    const int idx = cols[ce];
    float v;
    {
        const int ve = min(s + j, nnz - 1);
        float vv = vals[ve];
        if (DROPOUT) vv *= dropout_mul((unsigned)ve);
        v = (j < len) ? vv : 0.0f;
    }

    float ovf[NROWS];
#pragma unroll
    for (int qq = 0; qq < NROWS; ++qq) ovf[qq] = 0.0f;
    if (__any(len > SLOTS)) {
#pragma unroll
        for (int qq = 0; qq < NROWS; ++qq) {
            const int rs = rl_i(s, qq * SLOTS);
            const int re = rl_i(e, qq * SLOTS);
            for (int t = rs + SLOTS; t < re; ++t) {
                const int c = cols[t];
                float vv = vals[t];
                if (DROPOUT) vv *= dropout_mul((unsigned)t);
                ovf[qq] = fmaf(vv, x[((size_t)(unsigned)c << 6) + lane], ovf[qq]);
            }
        }
    }

    float xv[RING];
#pragma unroll
    for (int u = 0; u < RING; ++u) {
        xv[u] = x[((size_t)(unsigned)rl_i(idx, u) << 6) + lane];
    }

    float acc = 0.0f;
#pragma unroll
    for (int k = 0; k < T; ++k) {
        const float xc = xv[k % RING];
        if (k + RING < T) {
            xv[k % RING] = x[((size_t)(unsigned)rl_i(idx, k + RING) << 6) + lane];
        }
        acc = fmaf(rl_f(v, k), xc, acc);
        if ((k % SLOTS) == SLOTS - 1) {
            const int qk = k / SLOTS;
            y[((size_t)(r0 + qk) << 6) + lane] = acc + ovf[qk];
            acc = 0.0f;
        }
    }
}

static inline int blocks_for_waves(int waves) {
    return (waves + 3) / 4;  // 4 waves (256 threads) per block
}

extern "C" void kernel_launch(void* const* d_in, const int* in_sizes, int n_in,
                              void* d_out, int out_size, void* d_ws, size_t ws_size,
                              hipStream_t stream) {
    const float* item_emb = (const float*)d_in[0];
    const float* S_vals   = (const float*)d_in[1];
    const int*   S_rows   = (const int*)  d_in[2];
    const int*   S_cols   = (const int*)  d_in[3];
    const float* urm_vals = (const float*)d_in[4];
    const int*   urm_rows = (const int*)  d_in[5];
    const int*   urm_cols = (const int*)  d_in[6];

    const int nnzS = in_sizes[1];
    const int nnzU = in_sizes[4];

    float* user_out = (float*)d_out;          // U*E floats (output 0)
    float* x_out    = (float*)d_out + UE;     // I*E floats (output 1)

    // Workspace: rpS | rpU | hA | hB (dim-blocked fp16, 12.8 MB each) | mvU
    const size_t rpS_b = ((size_t)(I_CNT + 1) * 4 + 255) & ~(size_t)255;
    const size_t rpU_b = ((size_t)(U_CNT + 1) * 4 + 255) & ~(size_t)255;
    const size_t h_b   = (((size_t)IE * 2) + 255) & ~(size_t)255;
    const size_t mv_b  = (((size_t)nnzU * 4) + 255) & ~(size_t)255;
    int* rpS = (int*)d_ws;
    int* rpU = (int*)((char*)d_ws + rpS_b);
    unsigned short* hA = (unsigned short*)((char*)d_ws + rpS_b + rpU_b);
    unsigned short* hB = (unsigned short*)((char*)hA + h_b);
    float* mvU = (float*)((char*)hB + h_b);
    const size_t need_base = rpS_b + rpU_b + 2 * h_b;
    const size_t need_full = need_base + mv_b;

    const dim3 blk(256);

    // Build CSR row pointers (rows arrays are sorted).
    build_row_ptr<<<(nnzS + 255) / 256, blk, 0, stream>>>(S_rows, rpS, nnzS, I_CNT);
    build_row_ptr<<<(nnzU + 255) / 256, blk, 0, stream>>>(urm_rows, rpU, nnzU, U_CNT);

    if (ws_size >= need_base) {
        // phased dim-blocked fp16 pipeline
        f32_to_f16_blk<<<(IE / 4 + 255) / 256, blk, 0, stream>>>(
            (const float4*)item_emb, hA, IE / 4);

        // S hops: 2 rows/wave x 32 slots; 50,000 waves/phase.
        const int wS   = I_CNT / 2;
        const int bppS = (blocks_for_waves(wS) + 0);
        const dim3 gS(NPH * bppS);
        // hop 1: hA -> hB (blocked fp16 only)
        spmm_ph<false, 2, 32, false, true><<<gS, blk, 0, stream>>>(
            S_vals, rpS, S_cols, hA, nullptr, hB, I_CNT, nnzS, bppS);
        // hop 2: hB -> hA
        spmm_ph<false, 2, 32, false, true><<<gS, blk, 0, stream>>>(
            S_vals, rpS, S_cols, hB, nullptr, hA, I_CNT, nnzS, bppS);
        // hop 3: hA -> x_out (fp32 FINAL, standard layout) + hB (blocked shadow)
        spmm_ph<false, 2, 32, true, true><<<gS, blk, 0, stream>>>(
            S_vals, rpS, S_cols, hA, x_out, hB, I_CNT, nnzS, bppS);

        // URM: 1 row/wave x 48 slots; 131,072 waves/phase.
        const int bppU = blocks_for_waves(U_CNT);
        const dim3 gU(NPH * bppU);
        if (ws_size >= need_full) {
            // tier-1: premask vals once so the 4x-replicated waves skip threefry
            mask_vals<<<(nnzU + 255) / 256, blk, 0, stream>>>(urm_vals, mvU, nnzU);
            spmm_ph<false, 1, 48, true, false><<<gU, blk, 0, stream>>>(
                mvU, rpU, urm_cols, hB, user_out, nullptr, U_CNT, nnzU, bppU);
        } else {
            // tier-2: in-kernel dropout (threefry per phase; same result)
            spmm_ph<true, 1, 48, true, false><<<gU, blk, 0, stream>>>(
                urm_vals, rpU, urm_cols, hB, user_out, nullptr, U_CNT, nnzU, bppU);
        }
    } else {
        // tier-3: fp32 fallback (verified round-3 path).
        const int wS = I_CNT / 2;
        spmm_slots<false, 2, 24><<<blocks_for_waves(wS), blk, 0, stream>>>(
            S_vals, rpS, S_cols, item_emb, x_out, I_CNT, nnzS);
        spmm_slots<false, 2, 24><<<blocks_for_waves(wS), blk, 0, stream>>>(
            S_vals, rpS, S_cols, x_out, user_out, I_CNT, nnzS);
        spmm_slots<false, 2, 24><<<blocks_for_waves(wS), blk, 0, stream>>>(
            S_vals, rpS, S_cols, user_out, x_out, I_CNT, nnzS);
        spmm_slots<true, 1, 48><<<blocks_for_waves(U_CNT), blk, 0, stream>>>(
            urm_vals, rpU, urm_cols, x_out, user_out, U_CNT, nnzU);
    }
}

// Round 9
// 312.188 us; speedup vs baseline: 1.8598x; 1.8598x over previous
//
#include <hip/hip_runtime.h>
#include <hip/hip_fp16.h>

// Problem constants (from reference)
#define I_CNT 100000
#define U_CNT 131072
#define E_DIM 64
#define IE (I_CNT * E_DIM)          // 6,400,000 floats
#define UE ((size_t)U_CNT * E_DIM)  // 8,388,608 floats

#define DEPTH 32  // fp32-fallback ring depth

// ---------------- threefry2x32 (verified vs Random123 test vector) ----------------
__device__ __forceinline__ unsigned rotl32(unsigned v, int n) {
    return (v << n) | (v >> (32 - n));
}
__device__ __forceinline__ void threefry2x32(unsigned k0, unsigned k1,
                                             unsigned x0, unsigned x1,
                                             unsigned& o0, unsigned& o1) {
    unsigned k2 = k0 ^ k1 ^ 0x1BD11BDAu;
    x0 += k0; x1 += k1;
#define RND(r) { x0 += x1; x1 = rotl32(x1, r); x1 ^= x0; }
    RND(13) RND(15) RND(26) RND(6)   x0 += k1; x1 += k2 + 1u;
    RND(17) RND(29) RND(16) RND(24)  x0 += k2; x1 += k0 + 2u;
    RND(13) RND(15) RND(26) RND(6)   x0 += k0; x1 += k1 + 3u;
    RND(17) RND(29) RND(16) RND(24)  x0 += k1; x1 += k2 + 4u;
    RND(13) RND(15) RND(26) RND(6)   x0 += k2; x1 += k0 + 5u;
#undef RND
    o0 = x0; o1 = x1;
}

// Dropout mask, MEASURED (R8 discriminator probe): ctr=(0,e), XOR fold,
// u = bitcast((bits>>9)|0x3f800000)-1; keep iff u < 0.8; rescale 1/0.8.
__device__ __forceinline__ float dropout_mul(unsigned e) {
    unsigned o0, o1;
    threefry2x32(0u, 42u, 0u, e, o0, o1);
    const unsigned bits = o0 ^ o1;
    const float u = __uint_as_float((bits >> 9) | 0x3f800000u) - 1.0f;
    return (u < 0.8f) ? 1.25f : 0.0f;
}

// Compile-time-index lane broadcasts -> v_readlane with immediate (uniform result).
__device__ __forceinline__ int rl_i(int v, int l) {
    return __builtin_amdgcn_readlane(v, l);
}
__device__ __forceinline__ float rl_f(float v, int l) {
    return __int_as_float(__builtin_amdgcn_readlane(__float_as_int(v), l));
}

// fp16 pack/unpack (RTN via __float2half); unpack+fmaf is the v_fma_mix pattern.
__device__ __forceinline__ float2 unpack_h2(unsigned u) {
    float2 f;
    f.x = __half2float(__ushort_as_half((unsigned short)(u & 0xffffu)));
    f.y = __half2float(__ushort_as_half((unsigned short)(u >> 16)));
    return f;
}
__device__ __forceinline__ unsigned pack_h2(float a, float b) {
    const unsigned ha = __half_as_ushort(__float2half(a));
    const unsigned hb = __half_as_ushort(__float2half(b));
    return ha | (hb << 16);
}

// ---------------- row_ptr builder (rows are sorted) ----------------
__global__ void build_row_ptr(const int* __restrict__ rows,
                              int* __restrict__ row_ptr,
                              int nnz, int n_rows) {
    const int e = blockIdx.x * blockDim.x + threadIdx.x;
    if (e >= nnz) return;
    const int r  = rows[e];
    const int rp = (e == 0) ? -1 : rows[e - 1];
    for (int q = rp + 1; q <= r; ++q) row_ptr[q] = e;
    if (e == nnz - 1) {
        for (int q = r + 1; q <= n_rows; ++q) row_ptr[q] = nnz;
    }
}

// ---------------- fp32 -> fp16 convert (vectorized, linear layout) ----------------
__global__ __launch_bounds__(256) void f32_to_f16_vec(const float4* __restrict__ in,
                                                      unsigned long long* __restrict__ out,
                                                      int n4) {
    const int i = blockIdx.x * blockDim.x + threadIdx.x;
    if (i >= n4) return;
    const float4 f = in[i];
    const unsigned long long lo = pack_h2(f.x, f.y);
    const unsigned long long hi = pack_h2(f.z, f.w);
    __builtin_nontemporal_store(lo | (hi << 32), &out[i]);
}

// ---------------- quad-edge fp16-source slotted CSR SpMM (VERIFIED round 6) ----------
// 4 edge-groups of 16 lanes; each lane loads dwordx2 = 4 fp16 dims -> ONE
// instruction gathers FOUR x-rows (1 line-request per edge = request-optimal).
// Slot->lane broadcasts via __shfl (LDS pipe). fp32 values, fp32 accum.
template <bool DROPOUT, int NROWS, int SLOTS, bool OUT32, bool OUT16>
__global__ __launch_bounds__(256) void spmm_q(const float* __restrict__ vals,
                                              const int* __restrict__ row_ptr,
                                              const int* __restrict__ cols,
                                              const unsigned short* __restrict__ xh,
                                              float* __restrict__ y32,
                                              unsigned short* __restrict__ y16,
                                              int n_rows, int nnz) {
    constexpr int T     = NROWS * SLOTS;  // total edge slots per wave (<= 64)
    constexpr int QUADS = T / 4;          // gather instructions per wave
    constexpr int QPR   = SLOTS / 4;      // quads per row
    static_assert(T <= 64 && (SLOTS % 4) == 0, "slots must quad-align");

    const int lane = threadIdx.x & 63;
    const int wave = blockIdx.x * (blockDim.x >> 6) + (threadIdx.x >> 6);
    const int r0   = wave * NROWS;
    if (r0 >= n_rows) return;

    const int q  = min(lane / SLOTS, NROWS - 1);
    const int jr = lane - q * SLOTS;
    const int rq = r0 + q;

    const int s   = row_ptr[rq];
    const int e   = row_ptr[rq + 1];
    const int len = e - s;

    int ce = s + min(jr, max(len - 1, 0));
    ce = min(ce, nnz - 1);
    const int idx = __builtin_nontemporal_load(&cols[ce]);
    float v;
    {
        const int ve = min(s + jr, nnz - 1);
        float vv = __builtin_nontemporal_load(&vals[ve]);
        if (DROPOUT) vv *= dropout_mul((unsigned)ve);
        v = (jr < len) ? vv : 0.0f;
    }
    const int coff = idx << 7;  // byte offset of this slot's fp16 x-row (128 B)

    const int g    = lane >> 4;   // edge-group 0..3
    const int m    = lane & 15;   // dim-quad index (dims 4m..4m+3)
    const int moff = m << 3;      // byte offset within row
    const char* __restrict__ xb = (const char*)xh;

    float4 ovf[NROWS];
#pragma unroll
    for (int qq = 0; qq < NROWS; ++qq) ovf[qq] = make_float4(0.f, 0.f, 0.f, 0.f);
    if (__any(len > SLOTS)) {
#pragma unroll
        for (int qq = 0; qq < NROWS; ++qq) {
            const int rs = rl_i(s, qq * SLOTS);
            const int re = rl_i(e, qq * SLOTS);
            for (int t = rs + SLOTS; t < re; ++t) {
                if (g == 0) {
                    const int c = cols[t];
                    float vv = vals[t];
                    if (DROPOUT) vv *= dropout_mul((unsigned)t);
                    const uint2 u = *(const uint2*)(xb + (c << 7) + moff);
                    const float2 f01 = unpack_h2(u.x);
                    const float2 f23 = unpack_h2(u.y);
                    ovf[qq].x = fmaf(vv, f01.x, ovf[qq].x);
                    ovf[qq].y = fmaf(vv, f01.y, ovf[qq].y);
                    ovf[qq].z = fmaf(vv, f23.x, ovf[qq].z);
                    ovf[qq].w = fmaf(vv, f23.y, ovf[qq].w);
                }
            }
        }
    }

    uint2 xq[QUADS];
#pragma unroll
    for (int k = 0; k < QUADS; ++k) {
        const int co = __shfl(coff, 4 * k + g);   // ds_bpermute (LDS pipe)
        xq[k] = *(const uint2*)(xb + co + moff);
    }

    float4 acc = make_float4(0.f, 0.f, 0.f, 0.f);
#pragma unroll
    for (int k = 0; k < QUADS; ++k) {
        const float vv = __shfl(v, 4 * k + g);    // ds_bpermute (LDS pipe)
        const float2 f01 = unpack_h2(xq[k].x);
        const float2 f23 = unpack_h2(xq[k].y);
        acc.x = fmaf(vv, f01.x, acc.x);
        acc.y = fmaf(vv, f01.y, acc.y);
        acc.z = fmaf(vv, f23.x, acc.z);
        acc.w = fmaf(vv, f23.y, acc.w);
        if ((k % QPR) == QPR - 1) {               // compile-time flush point
            const int qk = k / QPR;               // compile-time row-of-group
            float ax = acc.x + ovf[qk].x;
            float ay = acc.y + ovf[qk].y;
            float az = acc.z + ovf[qk].z;
            float aw = acc.w + ovf[qk].w;
            ax += __shfl_xor(ax, 16); ax += __shfl_xor(ax, 32);
            ay += __shfl_xor(ay, 16); ay += __shfl_xor(ay, 32);
            az += __shfl_xor(az, 16); az += __shfl_xor(az, 32);
            aw += __shfl_xor(aw, 16); aw += __shfl_xor(aw, 32);
            const size_t rowoff = ((size_t)(r0 + qk)) << 6;
            if (lane < 16) {
                if constexpr (OUT32) {
                    *(float4*)(y32 + rowoff + (m << 2)) = make_float4(ax, ay, az, aw);
                }
            } else if (lane < 32) {
                if constexpr (OUT16) {
                    const unsigned px = pack_h2(ax, ay);
                    const unsigned py = pack_h2(az, aw);
                    *(uint2*)(y16 + rowoff + (m << 2)) = make_uint2(px, py);
                }
            }
            acc = make_float4(0.f, 0.f, 0.f, 0.f);
        }
    }
    (void)y32; (void)y16;
}

// ---------------- S-hop kernel: EPL=2, T=96 (MLP doubler) ----------------
// Same verified structure as spmm_q, but each lane owns TWO edge slots:
// reg A = slots 0..63 (lane), reg B = slots 64..95 (lanes 0..31).
// NROWS=4 x SLOTS=24 -> 96 edges/wave, 24 quad-loads issued up-front ->
// 96 outstanding gather lines per wave (2x round-6). Loads 0..15 broadcast
// from reg A, 16..23 from reg B (compile-time branch in the unrolled loop).
template <bool OUT32, bool OUT16>
__global__ __launch_bounds__(256) void spmm_s4(const float* __restrict__ vals,
                                               const int* __restrict__ row_ptr,
                                               const int* __restrict__ cols,
                                               const unsigned short* __restrict__ xh,
                                               float* __restrict__ y32,
                                               unsigned short* __restrict__ y16,
                                               int n_rows, int nnz) {
    constexpr int NROWS = 4, SLOTS = 24;
    constexpr int T = NROWS * SLOTS;      // 96
    constexpr int LOADS = T / 4;          // 24
    constexpr int QPR = SLOTS / 4;        // 6 loads per row

    const int lane = threadIdx.x & 63;
    const int wave = blockIdx.x * (blockDim.x >> 6) + (threadIdx.x >> 6);
    const int r0   = wave * NROWS;
    if (r0 >= n_rows) return;

    // --- assignment A: slot = lane (0..63 -> rows 0..2) ---
    const int qA = lane / SLOTS;
    const int jA = lane - qA * SLOTS;
    const int sA = row_ptr[r0 + qA];
    const int eA = row_ptr[r0 + qA + 1];
    const int lenA = eA - sA;
    int ceA = min(sA + min(jA, max(lenA - 1, 0)), nnz - 1);
    const int idxA = __builtin_nontemporal_load(&cols[ceA]);
    float vAv;
    {
        const int ve = min(sA + jA, nnz - 1);
        const float vv = __builtin_nontemporal_load(&vals[ve]);
        vAv = (jA < lenA) ? vv : 0.0f;
    }
    const int coffA = idxA << 7;

    // --- assignment B: slot = 64 + lane for lanes 0..31 (rows 2..3) ---
    const int lB  = min(lane, 31);
    const int sBi = 64 + lB;
    const int qB  = sBi / SLOTS;          // 2..3
    const int jB  = sBi - qB * SLOTS;
    const int sB  = row_ptr[r0 + qB];
    const int eB  = row_ptr[r0 + qB + 1];
    const int lenB = eB - sB;
    int ceB = min(sB + min(jB, max(lenB - 1, 0)), nnz - 1);
    const int idxB = __builtin_nontemporal_load(&cols[ceB]);
    float vBv;
    {
        const int ve = min(sB + jB, nnz - 1);
        const float vv = __builtin_nontemporal_load(&vals[ve]);
        vBv = (jB < lenB && lane < 32) ? vv : 0.0f;
    }
    const int coffB = idxB << 7;

    const int g    = lane >> 4;   // edge-group 0..3
    const int m    = lane & 15;   // dim-quad (dims 4m..4m+3)
    const int moff = m << 3;
    const char* __restrict__ xb = (const char*)xh;

    // COLD path: any of the 4 rows longer than SLOTS (rare, ~1%/row).
    float4 ovf[NROWS];
#pragma unroll
    for (int qq = 0; qq < NROWS; ++qq) ovf[qq] = make_float4(0.f, 0.f, 0.f, 0.f);
    const int lenBm = (lane < 32) ? lenB : 0;
    if (__any(lenA > SLOTS) || __any(lenBm > SLOTS)) {
#pragma unroll
        for (int qq = 0; qq < NROWS; ++qq) {
            // row qq starts at slot 24*qq: qq<3 -> reg A lane 24qq; qq==3 -> reg B lane 8
            const int rs = (qq < 3) ? rl_i(sA, qq * SLOTS) : rl_i(sB, 8);
            const int re = (qq < 3) ? rl_i(eA, qq * SLOTS) : rl_i(eB, 8);
            for (int t = rs + SLOTS; t < re; ++t) {
                if (g == 0) {
                    const int c = cols[t];
                    const float vv = vals[t];
                    const uint2 u = *(const uint2*)(xb + (c << 7) + moff);
                    const float2 f01 = unpack_h2(u.x);
                    const float2 f23 = unpack_h2(u.y);
                    ovf[qq].x = fmaf(vv, f01.x, ovf[qq].x);
                    ovf[qq].y = fmaf(vv, f01.y, ovf[qq].y);
                    ovf[qq].z = fmaf(vv, f23.x, ovf[qq].z);
                    ovf[qq].w = fmaf(vv, f23.y, ovf[qq].w);
                }
            }
        }
    }

    // HOT path: issue ALL 24 quad-gathers up front (96 lines in flight).
    uint2 xq[LOADS];
#pragma unroll
    for (int k = 0; k < LOADS; ++k) {
        const int slot = 4 * k + g;
        const int co = (k < 16) ? __shfl(coffA, slot) : __shfl(coffB, slot - 64);
        xq[k] = *(const uint2*)(xb + co + moff);
    }

    float4 acc = make_float4(0.f, 0.f, 0.f, 0.f);
#pragma unroll
    for (int k = 0; k < LOADS; ++k) {
        const int slot = 4 * k + g;
        const float vv = (k < 16) ? __shfl(vAv, slot) : __shfl(vBv, slot - 64);
        const float2 f01 = unpack_h2(xq[k].x);
        const float2 f23 = unpack_h2(xq[k].y);
        acc.x = fmaf(vv, f01.x, acc.x);
        acc.y = fmaf(vv, f01.y, acc.y);
        acc.z = fmaf(vv, f23.x, acc.z);
        acc.w = fmaf(vv, f23.y, acc.w);
        if ((k % QPR) == QPR - 1) {               // compile-time flush point
            const int qk = k / QPR;               // row-of-group 0..3
            float ax = acc.x + ovf[qk].x;
            float ay = acc.y + ovf[qk].y;
            float az = acc.z + ovf[qk].z;
            float aw = acc.w + ovf[qk].w;
            ax += __shfl_xor(ax, 16); ax += __shfl_xor(ax, 32);
            ay += __shfl_xor(ay, 16); ay += __shfl_xor(ay, 32);
            az += __shfl_xor(az, 16); az += __shfl_xor(az, 32);
            aw += __shfl_xor(aw, 16); aw += __shfl_xor(aw, 32);
            const size_t rowoff = ((size_t)(r0 + qk)) << 6;
            if (lane < 16) {
                if constexpr (OUT32) {
                    *(float4*)(y32 + rowoff + (m << 2)) = make_float4(ax, ay, az, aw);
                }
            } else if (lane < 32) {
                if constexpr (OUT16) {
                    const unsigned px = pack_h2(ax, ay);
                    const unsigned py = pack_h2(az, aw);
                    *(uint2*)(y16 + rowoff + (m << 2)) = make_uint2(px, py);
                }
            }
            acc = make_float4(0.f, 0.f, 0.f, 0.f);
        }
    }
    (void)y32; (void)y16;
}

// ---------------- fp32 fallback (verified round-3 kernel, unchanged) ----------------
template <bool DROPOUT, int NROWS, int SLOTS>
__global__ __launch_bounds__(256) void spmm_slots(const float* __restrict__ vals,
                                                  const int* __restrict__ row_ptr,
                                                  const int* __restrict__ cols,
                                                  const float* __restrict__ x,
                                                  float* __restrict__ y,
                                                  int n_rows, int nnz) {
    constexpr int T = NROWS * SLOTS;
    static_assert(T <= 64, "slots must fit one wave");
    constexpr int RING = (DEPTH < T) ? DEPTH : T;

    const int lane = threadIdx.x & 63;
    const int wave = blockIdx.x * (blockDim.x >> 6) + (threadIdx.x >> 6);
    const int r0   = wave * NROWS;
    if (r0 >= n_rows) return;

    const int q  = min(lane / SLOTS, NROWS - 1);
    const int j  = lane - q * SLOTS;
    const int rq = r0 + q;

    const int s   = row_ptr[rq];
    const int e   = row_ptr[rq + 1];
    const int len = e - s;

    int ce = s + min(j, max(len - 1, 0));
    ce = min(ce, nnz - 1);
    const int idx = cols[ce];
    float v;
    {
        const int ve = min(s + j, nnz - 1);
        float vv = vals[ve];
        if (DROPOUT) vv *= dropout_mul((unsigned)ve);
        v = (j < len) ? vv : 0.0f;
    }

    float ovf[NROWS];
#pragma unroll
    for (int qq = 0; qq < NROWS; ++qq) ovf[qq] = 0.0f;
    if (__any(len > SLOTS)) {
#pragma unroll
        for (int qq = 0; qq < NROWS; ++qq) {
            const int rs = rl_i(s, qq * SLOTS);
            const int re = rl_i(e, qq * SLOTS);
            for (int t = rs + SLOTS; t < re; ++t) {
                const int c = cols[t];
                float vv = vals[t];
                if (DROPOUT) vv *= dropout_mul((unsigned)t);
                ovf[qq] = fmaf(vv, x[((size_t)(unsigned)c << 6) + lane], ovf[qq]);
            }
        }
    }

    float xv[RING];
#pragma unroll
    for (int u = 0; u < RING; ++u) {
        xv[u] = x[((size_t)(unsigned)rl_i(idx, u) << 6) + lane];
    }

    float acc = 0.0f;
#pragma unroll
    for (int k = 0; k < T; ++k) {
        const float xc = xv[k % RING];
        if (k + RING < T) {
            xv[k % RING] = x[((size_t)(unsigned)rl_i(idx, k + RING) << 6) + lane];
        }
        acc = fmaf(rl_f(v, k), xc, acc);
        if ((k % SLOTS) == SLOTS - 1) {
            const int qk = k / SLOTS;
            y[((size_t)(r0 + qk) << 6) + lane] = acc + ovf[qk];
            acc = 0.0f;
        }
    }
}

static inline int blocks_for_waves(int waves) {
    return (waves + 3) / 4;  // 4 waves (256 threads) per block
}

extern "C" void kernel_launch(void* const* d_in, const int* in_sizes, int n_in,
                              void* d_out, int out_size, void* d_ws, size_t ws_size,
                              hipStream_t stream) {
    const float* item_emb = (const float*)d_in[0];
    const float* S_vals   = (const float*)d_in[1];
    const int*   S_rows   = (const int*)  d_in[2];
    const int*   S_cols   = (const int*)  d_in[3];
    const float* urm_vals = (const float*)d_in[4];
    const int*   urm_rows = (const int*)  d_in[5];
    const int*   urm_cols = (const int*)  d_in[6];

    const int nnzS = in_sizes[1];
    const int nnzU = in_sizes[4];

    float* user_out = (float*)d_out;          // U*E floats (output 0)
    float* x_out    = (float*)d_out + UE;     // I*E floats (output 1)

    // Workspace layout: rpS | rpU | hA (fp16 x, 12.8 MB) | hB (12.8 MB)
    const size_t rpS_b = ((size_t)(I_CNT + 1) * 4 + 255) & ~(size_t)255;
    const size_t rpU_b = ((size_t)(U_CNT + 1) * 4 + 255) & ~(size_t)255;
    const size_t h_b   = (((size_t)IE * 2) + 255) & ~(size_t)255;
    int* rpS = (int*)d_ws;
    int* rpU = (int*)((char*)d_ws + rpS_b);
    unsigned short* hA = (unsigned short*)((char*)d_ws + rpS_b + rpU_b);
    unsigned short* hB = (unsigned short*)((char*)hA + h_b);
    const size_t need = rpS_b + rpU_b + 2 * h_b;

    const dim3 blk(256);

    // Build CSR row pointers (rows arrays are sorted).
    build_row_ptr<<<(nnzS + 255) / 256, blk, 0, stream>>>(S_rows, rpS, nnzS, I_CNT);
    build_row_ptr<<<(nnzU + 255) / 256, blk, 0, stream>>>(urm_rows, rpU, nnzU, U_CNT);

    if (ws_size >= need) {
        // fp16-source pipeline: halved gather line traffic + working set.
        f32_to_f16_vec<<<(IE / 4 + 255) / 256, blk, 0, stream>>>(
            (const float4*)item_emb, (unsigned long long*)hA, IE / 4);

        // S hops: EPL=2 kernel, 4 rows/wave x 24 slots (T=96, 24 loads in flight).
        const int wS = I_CNT / 4;  // 25,000 waves (100000 % 4 == 0)
        // hop 1: hA -> hB (fp16 only; x1 never output)
        spmm_s4<false, true><<<blocks_for_waves(wS), blk, 0, stream>>>(
            S_vals, rpS, S_cols, hA, nullptr, hB, I_CNT, nnzS);
        // hop 2: hB -> hA
        spmm_s4<false, true><<<blocks_for_waves(wS), blk, 0, stream>>>(
            S_vals, rpS, S_cols, hB, nullptr, hA, I_CNT, nnzS);
        // hop 3: hA -> x_out (fp32 FINAL) + hB (fp16 shadow for URM)
        spmm_s4<true, true><<<blocks_for_waves(wS), blk, 0, stream>>>(
            S_vals, rpS, S_cols, hA, x_out, hB, I_CNT, nnzS);

        // URM: verified round-6 kernel, 1 row/wave x 48 slots, in-kernel dropout.
        spmm_q<true, 1, 48, true, false><<<blocks_for_waves(U_CNT), blk, 0, stream>>>(
            urm_vals, rpU, urm_cols, hB, user_out, nullptr, U_CNT, nnzU);
    } else {
        // fp32 fallback (verified round-3 path).
        const int wS = I_CNT / 2;
        spmm_slots<false, 2, 24><<<blocks_for_waves(wS), blk, 0, stream>>>(
            S_vals, rpS, S_cols, item_emb, x_out, I_CNT, nnzS);
        spmm_slots<false, 2, 24><<<blocks_for_waves(wS), blk, 0, stream>>>(
            S_vals, rpS, S_cols, x_out, user_out, I_CNT, nnzS);
        spmm_slots<false, 2, 24><<<blocks_for_waves(wS), blk, 0, stream>>>(
            S_vals, rpS, S_cols, user_out, x_out, I_CNT, nnzS);
        spmm_slots<true, 1, 48><<<blocks_for_waves(U_CNT), blk, 0, stream>>>(
            urm_vals, rpU, urm_cols, x_out, user_out, U_CNT, nnzU);
    }
}

// Round 11
// 301.849 us; speedup vs baseline: 1.9235x; 1.0343x over previous
//
#include <hip/hip_runtime.h>
#include <hip/hip_fp16.h>

// Problem constants (from reference)
#define I_CNT 100000
#define U_CNT 131072
#define E_DIM 64
#define IE (I_CNT * E_DIM)          // 6,400,000 floats
#define UE ((size_t)U_CNT * E_DIM)  // 8,388,608 floats

#define DEPTH 32  // fp32-fallback ring depth

// ---------------- threefry2x32 (verified vs Random123 test vector) ----------------
__device__ __forceinline__ unsigned rotl32(unsigned v, int n) {
    return (v << n) | (v >> (32 - n));
}
__device__ __forceinline__ void threefry2x32(unsigned k0, unsigned k1,
                                             unsigned x0, unsigned x1,
                                             unsigned& o0, unsigned& o1) {
    unsigned k2 = k0 ^ k1 ^ 0x1BD11BDAu;
    x0 += k0; x1 += k1;
#define RND(r) { x0 += x1; x1 = rotl32(x1, r); x1 ^= x0; }
    RND(13) RND(15) RND(26) RND(6)   x0 += k1; x1 += k2 + 1u;
    RND(17) RND(29) RND(16) RND(24)  x0 += k2; x1 += k0 + 2u;
    RND(13) RND(15) RND(26) RND(6)   x0 += k0; x1 += k1 + 3u;
    RND(17) RND(29) RND(16) RND(24)  x0 += k1; x1 += k2 + 4u;
    RND(13) RND(15) RND(26) RND(6)   x0 += k2; x1 += k0 + 5u;
#undef RND
    o0 = x0; o1 = x1;
}

// Dropout mask, MEASURED (R8 discriminator probe): ctr=(0,e), XOR fold,
// u = bitcast((bits>>9)|0x3f800000)-1; keep iff u < 0.8; rescale 1/0.8.
__device__ __forceinline__ float dropout_mul(unsigned e) {
    unsigned o0, o1;
    threefry2x32(0u, 42u, 0u, e, o0, o1);
    const unsigned bits = o0 ^ o1;
    const float u = __uint_as_float((bits >> 9) | 0x3f800000u) - 1.0f;
    return (u < 0.8f) ? 1.25f : 0.0f;
}

// Compile-time-index lane broadcasts -> v_readlane with immediate (uniform result).
__device__ __forceinline__ int rl_i(int v, int l) {
    return __builtin_amdgcn_readlane(v, l);
}
__device__ __forceinline__ float rl_f(float v, int l) {
    return __int_as_float(__builtin_amdgcn_readlane(__float_as_int(v), l));
}

// fp16 pack/unpack (RTN via __float2half); unpack+fmaf is the v_fma_mix pattern.
__device__ __forceinline__ float2 unpack_h2(unsigned u) {
    float2 f;
    f.x = __half2float(__ushort_as_half((unsigned short)(u & 0xffffu)));
    f.y = __half2float(__ushort_as_half((unsigned short)(u >> 16)));
    return f;
}
__device__ __forceinline__ unsigned pack_h2(float a, float b) {
    const unsigned ha = __half_as_ushort(__float2half(a));
    const unsigned hb = __half_as_ushort(__float2half(b));
    return ha | (hb << 16);
}

// ---------------- row_ptr builder (rows are sorted) ----------------
__global__ void build_row_ptr(const int* __restrict__ rows,
                              int* __restrict__ row_ptr,
                              int nnz, int n_rows) {
    const int e = blockIdx.x * blockDim.x + threadIdx.x;
    if (e >= nnz) return;
    const int r  = rows[e];
    const int rp = (e == 0) ? -1 : rows[e - 1];
    for (int q = rp + 1; q <= r; ++q) row_ptr[q] = e;
    if (e == nnz - 1) {
        for (int q = r + 1; q <= n_rows; ++q) row_ptr[q] = nnz;
    }
}

// ---------------- fp32 -> fp16 convert (vectorized) ----------------
__global__ __launch_bounds__(256) void f32_to_f16_vec(const float4* __restrict__ in,
                                                      unsigned long long* __restrict__ out,
                                                      int n4) {
    const int i = blockIdx.x * blockDim.x + threadIdx.x;
    if (i >= n4) return;
    const float4 f = in[i];
    const unsigned long long lo = pack_h2(f.x, f.y);
    const unsigned long long hi = pack_h2(f.z, f.w);
    __builtin_nontemporal_store(lo | (hi << 32), &out[i]);
}

// ---------------- quad-edge fp16-source slotted CSR SpMM (VERIFIED round 6) ----------
// 4 edge-groups of 16 lanes; each lane loads dwordx2 = 4 fp16 dims -> ONE
// instruction gathers FOUR x-rows (1 line-request per edge = request-optimal).
// Slot->lane broadcasts via __shfl (LDS pipe). fp32 values, fp32 accum.
template <bool DROPOUT, int NROWS, int SLOTS, bool OUT32, bool OUT16>
__global__ __launch_bounds__(256) void spmm_q(const float* __restrict__ vals,
                                              const int* __restrict__ row_ptr,
                                              const int* __restrict__ cols,
                                              const unsigned short* __restrict__ xh,
                                              float* __restrict__ y32,
                                              unsigned short* __restrict__ y16,
                                              int n_rows, int nnz) {
    constexpr int T     = NROWS * SLOTS;  // total edge slots per wave (<= 64)
    constexpr int QUADS = T / 4;          // gather instructions per wave
    constexpr int QPR   = SLOTS / 4;      // quads per row
    static_assert(T <= 64 && (SLOTS % 4) == 0, "slots must quad-align");

    const int lane = threadIdx.x & 63;
    const int wave = blockIdx.x * (blockDim.x >> 6) + (threadIdx.x >> 6);
    const int r0   = wave * NROWS;
    if (r0 >= n_rows) return;

    const int q  = min(lane / SLOTS, NROWS - 1);
    const int jr = lane - q * SLOTS;
    const int rq = r0 + q;

    const int s   = row_ptr[rq];
    const int e   = row_ptr[rq + 1];
    const int len = e - s;

    int ce = s + min(jr, max(len - 1, 0));
    ce = min(ce, nnz - 1);
    const int idx = __builtin_nontemporal_load(&cols[ce]);
    float v;
    {
        const int ve = min(s + jr, nnz - 1);
        float vv = __builtin_nontemporal_load(&vals[ve]);
        if (DROPOUT) vv *= dropout_mul((unsigned)ve);
        v = (jr < len) ? vv : 0.0f;
    }
    const int coff = idx << 7;  // byte offset of this slot's fp16 x-row (128 B)

    const int g    = lane >> 4;   // edge-group 0..3
    const int m    = lane & 15;   // dim-quad index (dims 4m..4m+3)
    const int moff = m << 3;      // byte offset within row
    const char* __restrict__ xb = (const char*)xh;

    float4 ovf[NROWS];
#pragma unroll
    for (int qq = 0; qq < NROWS; ++qq) ovf[qq] = make_float4(0.f, 0.f, 0.f, 0.f);
    if (__any(len > SLOTS)) {
#pragma unroll
        for (int qq = 0; qq < NROWS; ++qq) {
            const int rs = rl_i(s, qq * SLOTS);
            const int re = rl_i(e, qq * SLOTS);
            for (int t = rs + SLOTS; t < re; ++t) {
                if (g == 0) {
                    const int c = cols[t];
                    float vv = vals[t];
                    if (DROPOUT) vv *= dropout_mul((unsigned)t);
                    const uint2 u = *(const uint2*)(xb + (c << 7) + moff);
                    const float2 f01 = unpack_h2(u.x);
                    const float2 f23 = unpack_h2(u.y);
                    ovf[qq].x = fmaf(vv, f01.x, ovf[qq].x);
                    ovf[qq].y = fmaf(vv, f01.y, ovf[qq].y);
                    ovf[qq].z = fmaf(vv, f23.x, ovf[qq].z);
                    ovf[qq].w = fmaf(vv, f23.y, ovf[qq].w);
                }
            }
        }
    }

    uint2 xq[QUADS];
#pragma unroll
    for (int k = 0; k < QUADS; ++k) {
        const int co = __shfl(coff, 4 * k + g);   // ds_bpermute (LDS pipe)
        xq[k] = *(const uint2*)(xb + co + moff);
    }

    float4 acc = make_float4(0.f, 0.f, 0.f, 0.f);
#pragma unroll
    for (int k = 0; k < QUADS; ++k) {
        const float vv = __shfl(v, 4 * k + g);    // ds_bpermute (LDS pipe)
        const float2 f01 = unpack_h2(xq[k].x);
        const float2 f23 = unpack_h2(xq[k].y);
        acc.x = fmaf(vv, f01.x, acc.x);
        acc.y = fmaf(vv, f01.y, acc.y);
        acc.z = fmaf(vv, f23.x, acc.z);
        acc.w = fmaf(vv, f23.y, acc.w);
        if ((k % QPR) == QPR - 1) {               // compile-time flush point
            const int qk = k / QPR;               // compile-time row-of-group
            float ax = acc.x + ovf[qk].x;
            float ay = acc.y + ovf[qk].y;
            float az = acc.z + ovf[qk].z;
            float aw = acc.w + ovf[qk].w;
            ax += __shfl_xor(ax, 16); ax += __shfl_xor(ax, 32);
            ay += __shfl_xor(ay, 16); ay += __shfl_xor(ay, 32);
            az += __shfl_xor(az, 16); az += __shfl_xor(az, 32);
            aw += __shfl_xor(aw, 16); aw += __shfl_xor(aw, 32);
            const size_t rowoff = ((size_t)(r0 + qk)) << 6;
            if (lane < 16) {
                if constexpr (OUT32) {
                    *(float4*)(y32 + rowoff + (m << 2)) = make_float4(ax, ay, az, aw);
                }
            } else if (lane < 32) {
                if constexpr (OUT16) {
                    const unsigned px = pack_h2(ax, ay);
                    const unsigned py = pack_h2(az, aw);
                    *(uint2*)(y16 + rowoff + (m << 2)) = make_uint2(px, py);
                }
            }
            acc = make_float4(0.f, 0.f, 0.f, 0.f);
        }
    }
    (void)y32; (void)y16;
}

// ---------------- fp32 fallback (verified round-3 kernel, unchanged) ----------------
template <bool DROPOUT, int NROWS, int SLOTS>
__global__ __launch_bounds__(256) void spmm_slots(const float* __restrict__ vals,
                                                  const int* __restrict__ row_ptr,
                                                  const int* __restrict__ cols,
                                                  const float* __restrict__ x,
                                                  float* __restrict__ y,
                                                  int n_rows, int nnz) {
    constexpr int T = NROWS * SLOTS;
    static_assert(T <= 64, "slots must fit one wave");
    constexpr int RING = (DEPTH < T) ? DEPTH : T;

    const int lane = threadIdx.x & 63;
    const int wave = blockIdx.x * (blockDim.x >> 6) + (threadIdx.x >> 6);
    const int r0   = wave * NROWS;
    if (r0 >= n_rows) return;

    const int q  = min(lane / SLOTS, NROWS - 1);
    const int j  = lane - q * SLOTS;
    const int rq = r0 + q;

    const int s   = row_ptr[rq];
    const int e   = row_ptr[rq + 1];
    const int len = e - s;

    int ce = s + min(j, max(len - 1, 0));
    ce = min(ce, nnz - 1);
    const int idx = cols[ce];
    float v;
    {
        const int ve = min(s + j, nnz - 1);
        float vv = vals[ve];
        if (DROPOUT) vv *= dropout_mul((unsigned)ve);
        v = (j < len) ? vv : 0.0f;
    }

    float ovf[NROWS];
#pragma unroll
    for (int qq = 0; qq < NROWS; ++qq) ovf[qq] = 0.0f;
    if (__any(len > SLOTS)) {
#pragma unroll
        for (int qq = 0; qq < NROWS; ++qq) {
            const int rs = rl_i(s, qq * SLOTS);
            const int re = rl_i(e, qq * SLOTS);
            for (int t = rs + SLOTS; t < re; ++t) {
                const int c = cols[t];
                float vv = vals[t];
                if (DROPOUT) vv *= dropout_mul((unsigned)t);
                ovf[qq] = fmaf(vv, x[((size_t)(unsigned)c << 6) + lane], ovf[qq]);
            }
        }
    }

    float xv[RING];
#pragma unroll
    for (int u = 0; u < RING; ++u) {
        xv[u] = x[((size_t)(unsigned)rl_i(idx, u) << 6) + lane];
    }

    float acc = 0.0f;
#pragma unroll
    for (int k = 0; k < T; ++k) {
        const float xc = xv[k % RING];
        if (k + RING < T) {
            xv[k % RING] = x[((size_t)(unsigned)rl_i(idx, k + RING) << 6) + lane];
        }
        acc = fmaf(rl_f(v, k), xc, acc);
        if ((k % SLOTS) == SLOTS - 1) {
            const int qk = k / SLOTS;
            y[((size_t)(r0 + qk) << 6) + lane] = acc + ovf[qk];
            acc = 0.0f;
        }
    }
}

static inline int blocks_for_waves(int waves) {
    return (waves + 3) / 4;  // 4 waves (256 threads) per block
}

extern "C" void kernel_launch(void* const* d_in, const int* in_sizes, int n_in,
                              void* d_out, int out_size, void* d_ws, size_t ws_size,
                              hipStream_t stream) {
    const float* item_emb = (const float*)d_in[0];
    const float* S_vals   = (const float*)d_in[1];
    const int*   S_rows   = (const int*)  d_in[2];
    const int*   S_cols   = (const int*)  d_in[3];
    const float* urm_vals = (const float*)d_in[4];
    const int*   urm_rows = (const int*)  d_in[5];
    const int*   urm_cols = (const int*)  d_in[6];

    const int nnzS = in_sizes[1];
    const int nnzU = in_sizes[4];

    float* user_out = (float*)d_out;          // U*E floats (output 0)
    float* x_out    = (float*)d_out + UE;     // I*E floats (output 1)

    // Workspace layout: rpS | rpU | hA (fp16 x, 12.8 MB) | hB (12.8 MB)
    const size_t rpS_b = ((size_t)(I_CNT + 1) * 4 + 255) & ~(size_t)255;
    const size_t rpU_b = ((size_t)(U_CNT + 1) * 4 + 255) & ~(size_t)255;
    const size_t h_b   = (((size_t)IE * 2) + 255) & ~(size_t)255;
    int* rpS = (int*)d_ws;
    int* rpU = (int*)((char*)d_ws + rpS_b);
    unsigned short* hA = (unsigned short*)((char*)d_ws + rpS_b + rpU_b);
    unsigned short* hB = (unsigned short*)((char*)hA + h_b);
    const size_t need = rpS_b + rpU_b + 2 * h_b;

    const dim3 blk(256);

    // Build CSR row pointers (rows arrays are sorted).
    build_row_ptr<<<(nnzS + 255) / 256, blk, 0, stream>>>(S_rows, rpS, nnzS, I_CNT);
    build_row_ptr<<<(nnzU + 255) / 256, blk, 0, stream>>>(urm_rows, rpU, nnzU, U_CNT);

    if (ws_size >= need) {
        // fp16-source pipeline: halved gather line traffic + working set.
        f32_to_f16_vec<<<(IE / 4 + 255) / 256, blk, 0, stream>>>(
            (const float4*)item_emb, (unsigned long long*)hA, IE / 4);

        const int wS = I_CNT / 2;  // S hops: 2 rows/wave x 24 slots
        // hop 1: hA -> hB (fp16 only; x1 never output)
        spmm_q<false, 2, 24, false, true><<<blocks_for_waves(wS), blk, 0, stream>>>(
            S_vals, rpS, S_cols, hA, nullptr, hB, I_CNT, nnzS);
        // hop 2: hB -> hA
        spmm_q<false, 2, 24, false, true><<<blocks_for_waves(wS), blk, 0, stream>>>(
            S_vals, rpS, S_cols, hB, nullptr, hA, I_CNT, nnzS);
        // hop 3: hA -> x_out (fp32 FINAL) + hB (fp16 shadow for URM)
        spmm_q<false, 2, 24, true, true><<<blocks_for_waves(wS), blk, 0, stream>>>(
            S_vals, rpS, S_cols, hA, x_out, hB, I_CNT, nnzS);
        // URM: 1 row/wave x 48 slots, in-kernel dropout (original edge index).
        spmm_q<true, 1, 48, true, false><<<blocks_for_waves(U_CNT), blk, 0, stream>>>(
            urm_vals, rpU, urm_cols, hB, user_out, nullptr, U_CNT, nnzU);
    } else {
        // fp32 fallback (verified round-3 path).
        const int wS = I_CNT / 2;
        spmm_slots<false, 2, 24><<<blocks_for_waves(wS), blk, 0, stream>>>(
            S_vals, rpS, S_cols, item_emb, x_out, I_CNT, nnzS);
        spmm_slots<false, 2, 24><<<blocks_for_waves(wS), blk, 0, stream>>>(
            S_vals, rpS, S_cols, x_out, user_out, I_CNT, nnzS);
        spmm_slots<false, 2, 24><<<blocks_for_waves(wS), blk, 0, stream>>>(
            S_vals, rpS, S_cols, user_out, x_out, I_CNT, nnzS);
        spmm_slots<true, 1, 48><<<blocks_for_waves(U_CNT), blk, 0, stream>>>(
            urm_vals, rpU, urm_cols, x_out, user_out, U_CNT, nnzU);
    }
}